// Round 7
// baseline (6947.397 us; speedup 1.0000x reference)
//
#include <hip/hip_runtime.h>
#include <hip/hip_bf16.h>

// TTS: embed -> BiLSTM encoder -> K/V proj -> 1000-step autoregressive decode.
// v8 decode (fix v7's LDS bank conflicts, drop another sync):
//  - v7's P5 read lWV as (rg=tid>>2,c4=tid&3): bank base (12rg+16c4)%32 ->
//    8-way conflict, 1.04e8 conflict-cycles (the whole v7 regression).
//    v8: thread tid<384 owns ONE full WV row (16 dot8 over 128 t, l_p reads
//    broadcast): consecutive lanes -> consecutive 272B-strided rows = the lK
//    QK pattern (measured 0 conflicts in v6). No shuffles; same 384 aadds.
//  - Prelude B t-loop staggered by c4 (kills 4-addr same-bank-quad reads).
//  - Sync-free mel/stop in the RT gap: per-8-lane complete dots from the
//    staggered l_hw replica + 3 shuffles + direct store. Gap sync, l_mt,
//    l_sp deleted -> 5 syncthreads/step (was 6).
//  - Rest as v7: WV=Wcg@V^T bf16 in LDS (prelude), 256 blocks=(b,h,half),
//    one RT/step via per-batch 768-float atomicAdd accum (rot-3, reset by
//    idle tid>=464), redundant h_t, f-gates skipped, t==1 partner wait.
// Sync: fence-free flag barriers; agent-scope RELAXED atomics. fp32 except
// bf16 Wcg/W2m/WV.

typedef unsigned short u16;
typedef unsigned int   u32;
#define DI __device__ __forceinline__

// ---- ws layout (bytes) ----
static constexpr size_t WS_BAR   = 0;              // int flag lines: [0,32KB) decode, 64KB+ enc
static constexpr size_t WS_GBUF  = 64*1024;        // fp32 [3][16][768] 144KB (zeroed by k_init)
static constexpr size_t WS_HBUF  = 192*1024;       // legacy zero region
static constexpr size_t WS_PROBS = 208*1024;       // fp32 [16][8][128] 64KB
static constexpr size_t WS_BIAS  = 272*1024;       // fp32 bqp[512]|bg0[1024]|bgp[1024]
static constexpr size_t WS_W2M   = 320*1024;       // bf16 [1024][256] 512KB
static constexpr size_t WS_WQH   = 832*1024;       // fp32 [512][256]  512KB
static constexpr size_t WS_WCG   = 1344*1024;      // bf16 [1024][512] 1MB -> 2368KB

// ---- d_out scratch (float indices; d_out = 8,210,048 floats) ----
static constexpr size_t OF_ENC_A = 262144;         // fp32 [8][128][512] b=0..7
static constexpr size_t OF_ENC_B = 1286144;        // fp32 [8][128][512] b=8..15
static constexpr size_t OF_XWF   = 4015744;        // fp32 [2048][1024]
static constexpr size_t OF_XWB   = 6112896;        // fp32 [2048][1024] -> 8210048
// K/V slot (batch pair p=b>>1, sub s=b&1): outf + p*1024000 + s*131072 (K then V^T)

DI float bf2f(u16 u){ union{u32 i; float f;} v; v.i = ((u32)u)<<16; return v.f; }
DI u16 f2bf(float f){ union{float f; u32 i;} v; v.f = f;
  u32 r = v.i + 0x7fffu + ((v.i>>16)&1u); return (u16)(r>>16); }
DI float2 bf2x(u32 u){ union{u32 i; float f;} a,b; a.i = u<<16; b.i = u & 0xffff0000u;
  float2 r; r.x = a.f; r.y = b.f; return r; }
DI float dot8(uint4 wv, float4 a, float4 b){   // bf16 weights x fp32 acts
  float2 w0 = bf2x(wv.x), w1 = bf2x(wv.y), w2 = bf2x(wv.z), w3 = bf2x(wv.w);
  return w0.x*a.x + w0.y*a.y + w1.x*a.z + w1.y*a.w
       + w2.x*b.x + w2.y*b.y + w3.x*b.z + w3.y*b.w;
}
DI float dot8f(float4 wa, float4 wb, float4 a, float4 b){
  return wa.x*a.x + wa.y*a.y + wa.z*a.z + wa.w*a.w
       + wb.x*b.x + wb.y*b.y + wb.z*b.z + wb.w*b.w;
}
DI float sigm(float x){ return 1.f/(1.f + __expf(-x)); }

// agent-scope relaxed atomics: coherence-point access, no fence needed.
DI float afload(const float* p){
  return __hip_atomic_load(p, __ATOMIC_RELAXED, __HIP_MEMORY_SCOPE_AGENT);
}
DI void afstore(float* p, float v){
  __hip_atomic_store(p, v, __ATOMIC_RELAXED, __HIP_MEMORY_SCOPE_AGENT);
}
DI void aadd(float* p, float v){
  __hip_atomic_fetch_add(p, v, __ATOMIC_RELAXED, __HIP_MEMORY_SCOPE_AGENT);
}

// ---- fence-free flag barrier ----
DI void bar_arrive(int* flags, int myidx, int t){
  __syncthreads();
  if (threadIdx.x == 0){
    __builtin_amdgcn_s_waitcnt(0);
    __hip_atomic_store(flags + myidx*32, t, __ATOMIC_RELAXED, __HIP_MEMORY_SCOPE_AGENT);
  }
}
DI void bar_wait(int* flags, int n, int t){
  if (threadIdx.x < 64){
    const int idx = threadIdx.x & (n-1);
    int v = __hip_atomic_load(flags + idx*32, __ATOMIC_RELAXED, __HIP_MEMORY_SCOPE_AGENT);
    while (__any(v < t)){
      __builtin_amdgcn_s_sleep(1);
      if (v < t)
        v = __hip_atomic_load(flags + idx*32, __ATOMIC_RELAXED, __HIP_MEMORY_SCOPE_AGENT);
    }
  }
  __asm__ __volatile__("" ::: "memory");
  __syncthreads();
}

__global__ __launch_bounds__(256) void k_init(int* bars, float* hbuf){
  const int i = blockIdx.x*256 + threadIdx.x;   // 32 blocks
  for (int k = i; k < 49152; k += 32*256) bars[k] = 0;
  if (i < 4096) hbuf[i] = 0.f;
}

// fused embed + x@Wih.T + biases -> xw fp32. 2048 blocks.
__global__ __launch_bounds__(256) void k_xw(
    const int* __restrict__ tok, const int* __restrict__ spk,
    const float* __restrict__ et, const float* __restrict__ es,
    const float* __restrict__ WihF, const float* __restrict__ bihF, const float* __restrict__ bhhF,
    const float* __restrict__ WihB, const float* __restrict__ bihB, const float* __restrict__ bhhB,
    float* __restrict__ xwf, float* __restrict__ xwb){
  const int tid = threadIdx.x, bi = blockIdx.x;
  const int dir = bi & 1, jc = (bi >> 1) & 3, btg = bi >> 3;
  const int j = jc*256 + tid;
  const float* W = (dir ? WihB : WihF) + j*256;
  const float bias = (dir ? bihB : bihF)[j] + (dir ? bhhB : bhhF)[j];
  float* xw = dir ? xwb : xwf;

  __shared__ __align__(16) float lx[8][256];
  #pragma unroll
  for (int r = 0; r < 8; ++r){
    const int bt = btg*8 + r;
    lx[r][tid] = et[tok[bt]*256 + tid] + es[spk[bt>>7]*256 + tid];
  }
  __syncthreads();

  float acc[8];
  #pragma unroll
  for (int k2 = 0; k2 < 8; ++k2) acc[k2] = bias;
  for (int h = 0; h < 256; h += 8){
    float4 w0 = *(const float4*)(W + h);
    float4 w1 = *(const float4*)(W + h + 4);
    #pragma unroll
    for (int k2 = 0; k2 < 8; ++k2)
      acc[k2] += dot8f(w0, w1, *(const float4*)(&lx[k2][h]), *(const float4*)(&lx[k2][h+4]));
  }
  #pragma unroll
  for (int k2 = 0; k2 < 8; ++k2) xw[(btg*8 + k2)*1024 + j] = acc[k2];
}

// Wcg = W1@Wo -> bf16 [1024,512]; W2m = W2@Wmel -> bf16 [1024,256];
// Wqh = Wq@Wmel -> fp32 [512,256]. 896 blocks.
__global__ __launch_bounds__(256) void k_fuse(
    const float* __restrict__ decW, const float* __restrict__ Wo,
    const float* __restrict__ Wmel, const float* __restrict__ Wq,
    u16* __restrict__ Wcg, u16* __restrict__ W2m, float* __restrict__ Wqh){
  const int tid = threadIdx.x, blk = blockIdx.x;
  float acc[4] = {0.f,0.f,0.f,0.f};
  if (blk < 512){
    const int g0 = (blk >> 1)*4, e = (blk & 1)*256 + tid;
    for (int jj = 0; jj < 512; ++jj){
      float wo = Wo[jj*512 + e];
      #pragma unroll
      for (int i2 = 0; i2 < 4; ++i2) acc[i2] += decW[(g0+i2)*1024 + jj] * wo;
    }
    #pragma unroll
    for (int i2 = 0; i2 < 4; ++i2) Wcg[(g0+i2)*512 + e] = f2bf(acc[i2]);
  } else if (blk < 768){
    const int g0 = (blk - 512)*4, h = tid;
    for (int m = 0; m < 512; ++m){
      float wm = Wmel[m*256 + h];
      #pragma unroll
      for (int i2 = 0; i2 < 4; ++i2) acc[i2] += decW[(g0+i2)*1024 + 512 + m] * wm;
    }
    #pragma unroll
    for (int i2 = 0; i2 < 4; ++i2) W2m[(g0+i2)*256 + h] = f2bf(acc[i2]);
  } else {
    const int j0 = (blk - 768)*4, h = tid;
    for (int e = 0; e < 512; ++e){
      float wm = Wmel[e*256 + h];
      #pragma unroll
      for (int i2 = 0; i2 < 4; ++i2) acc[i2] += Wq[(j0+i2)*512 + e] * wm;
    }
    #pragma unroll
    for (int i2 = 0; i2 < 4; ++i2) Wqh[(j0+i2)*256 + h] = acc[i2];
  }
}

__global__ __launch_bounds__(256) void k_bias(
    const float* __restrict__ Wq, const float* __restrict__ bq, const float* __restrict__ bmel,
    const float* __restrict__ decW, const float* __restrict__ bo,
    const float* __restrict__ bih, const float* __restrict__ bhh, float* __restrict__ biasws){
  const int o = blockIdx.x*256 + threadIdx.x;   // 6 blocks -> 1536
  if (o < 512){
    float s = bq[o];
    for (int e = 0; e < 512; ++e) s += Wq[o*512 + e] * bmel[e];
    biasws[o] = s;                               // bq' = Wq@bmel + bq
  } else {
    const int gr = o - 512;
    float s1 = bih[gr] + bhh[gr];
    for (int jj = 0; jj < 512; ++jj) s1 += decW[gr*1024 + jj] * bo[jj];
    biasws[512 + gr] = s1;                       // bg0 = W1@bo + bih + bhh
    float s2 = s1;
    for (int m = 0; m < 512; ++m) s2 += decW[gr*1024 + 512 + m] * bmel[m];
    biasws[1536 + gr] = s2;                      // bg' = bg0 + W2@bmel
  }
}

// persistent BiLSTM encoder: 32 groups (dir,b) x 8 WGs x 128 thr. fp32.
__global__ __launch_bounds__(128) void k_enc(
    const float* __restrict__ xwf, const float* __restrict__ xwb,
    const float* __restrict__ WhhF, const float* __restrict__ WhhB,
    float* encA, float* encB, int* bars){
  const int tid = threadIdx.x;
  const int xcd = blockIdx.x & 7, sl = blockIdx.x >> 3;
  const int grp = xcd*4 + (sl >> 3);
  const int w = sl & 7;
  const int dir = grp & 1, b = grp >> 1;
  int* bar = bars + (16 + grp)*1024;
  const float* Whh = dir ? WhhB : WhhF;
  const float* xw = dir ? xwb : xwf;
  float* encb = (b < 8 ? encA : encB) + (size_t)(b & 7)*65536;
  const int q = tid >> 5, ii = tid & 31;
  const int j = q*256 + w*32 + ii;
  const float* wr = Whh + j*256;

  __shared__ __align__(16) float l_h[256];
  __shared__ float l_g[4][32];
  __shared__ float l_c[32];
  if (tid < 32) l_c[tid] = 0.f;
  __syncthreads();

  for (int it = 0; it < 128; ++it){
    const int ts = dir ? (127 - it) : it;
    float acc = xw[(b*128 + ts)*1024 + j];
    if (it > 0){
      const int tp = dir ? (ts + 1) : (ts - 1);
      const float* hp = encb + tp*512 + dir*256;
      for (int i = tid; i < 256; i += 128) l_h[i] = afload(hp + i);
      __syncthreads();
      #pragma unroll 4
      for (int k = 0; k < 256; k += 8)
        acc += dot8f(*(const float4*)(wr + k), *(const float4*)(wr + k + 4),
                     *(const float4*)(&l_h[k]), *(const float4*)(&l_h[k + 4]));
    }
    l_g[q][ii] = acc;
    __syncthreads();
    if (tid < 32){
      float ig = l_g[0][tid], fg = l_g[1][tid], gg = l_g[2][tid], og = l_g[3][tid];
      float c = sigm(fg)*l_c[tid] + sigm(ig)*tanhf(gg);
      l_c[tid] = c;
      afstore(encb + ts*512 + dir*256 + w*32 + tid, sigm(og)*tanhf(c));
    }
    bar_arrive(bar, w, it+1);
    bar_wait(bar, 8, it+1);
  }
}

// K,V projections fp32 -> per-pair slot in d_out. 1024 blocks.
__global__ __launch_bounds__(256) void k_proj(
    const float* __restrict__ encA, const float* __restrict__ encB,
    const float* __restrict__ Wk, const float* __restrict__ bk,
    const float* __restrict__ Wv, const float* __restrict__ bv,
    float* outf){
  const int tid = threadIdx.x, x = blockIdx.x;
  const int role = x & 1, dc = (x >> 1) & 1, btg = x >> 2;
  const int row = dc*256 + tid;
  const float* W = (role ? Wv : Wk) + row*512;
  const float bias = (role ? bv : bk)[row];
  const int b = (btg*8) >> 7;
  const float* eb = (b < 8 ? encA : encB) + (size_t)(b & 7)*65536;
  float acc[8];
  #pragma unroll
  for (int k2 = 0; k2 < 8; ++k2) acc[k2] = bias;
  for (int e = 0; e < 512; e += 8){
    float4 wa = *(const float4*)(W + e);
    float4 wb = *(const float4*)(W + e + 4);
    #pragma unroll
    for (int k2 = 0; k2 < 8; ++k2){
      const float* ep = eb + ((btg*8 + k2) & 127)*512 + e;
      acc[k2] += dot8f(wa, wb, *(const float4*)(ep), *(const float4*)(ep + 4));
    }
  }
  const int head = row >> 6, dd = row & 63;
  float* kv = outf + (size_t)(b >> 1)*1024000 + (size_t)(b & 1)*131072;
  #pragma unroll
  for (int k2 = 0; k2 < 8; ++k2){
    const int ts = (btg*8 + k2) & 127;
    if (role == 0) kv[head*8192 + ts*64 + dd] = acc[k2];
    else           kv[65536 + head*8192 + dd*128 + ts] = acc[k2];
  }
}

// persistent decoder v8: 256 blocks = (b,h,half) x 512 thr. WV in LDS read
// row-per-lane (conflict-free); one RT/step; sync-free mel gap.
__global__ __launch_bounds__(512) void k_decode(
    const float* __restrict__ Wqh,   // [512][256] fp32
    const u16*   __restrict__ Wcg,   // [1024][512] bf16 (prelude only)
    const u16*   __restrict__ W2m,   // [1024][256] bf16
    const float* __restrict__ Wmel,  // [512][256] fp32 (streamed per step)
    const float* __restrict__ bmel,
    const float* __restrict__ Wstop, const float* __restrict__ bstop,
    const float* __restrict__ bq,    // original bq [512]
    const float* __restrict__ biasws,// bqp[512] | bg0[1024] | bgp[1024]
    float* Gbuf,                     // [3][16][768] gate accumulators (zeroed)
    float* probs, int* bars,
    float* out){                     // K/V slots alias mel region (prelude-only reads)
  const int tid = threadIdx.x;
  const int b = blockIdx.x & 15, sidx = blockIdx.x >> 4;   // batch, slot
  const int h = sidx >> 1, half = sidx & 1;                // head, row-half
  const int d = tid & 63, ko = tid >> 6;                   // 64 dims x 8 k-chunks
  int* bflag = bars + b*512;
  float* out_mel  = out;
  float* out_stop = out + 8192000;
  float* out_attn = out + 8208000;

  // lK: fp32 K stride 68 (conflict-free b128 rows); doubles as V staging temp.
  // lWV: bf16 [384 local rows][136] — this half's {i,g,o} rows x 128 t.
  __shared__ __align__(16) float lK[128*68];
  __shared__ __align__(16) u16  lWV[384*136];
  __shared__ __align__(16) float l_h[256];
  __shared__ __align__(16) float l_hw[8*36];    // staggered replica: chunk c at l_hw+c*36
  __shared__ __align__(16) float l_q[64];
  __shared__ __align__(16) float l_p[128];      // UNNORMALIZED exp(s-M)
  __shared__ __align__(16) float l_qt[8][64];   // q partials
  __shared__ float l_r[4];                      // [0]=S, [1]=1/S

  const float* kv = out + (size_t)(b >> 1)*1024000 + (size_t)(b & 1)*131072;
  const int rg = tid >> 2, c4 = tid & 3;        // prelude-B roles
  const int rw = tid >> 3, c8 = tid & 7;        // w2m roles
  const int r2 = half*384 + h*48 + rw;          // w2m packed row

  // ---- prelude A: stage V[t][dd] into lK temp (V^T in slot: [dd][128]) ----
  {
    const float* gV = kv + 65536 + h*8192;
    for (int i = tid; i < 8192; i += 512){
      const int dd = i >> 7, t = i & 127;
      lK[t*68 + dd] = gV[i];
    }
  }
  __syncthreads();
  // ---- prelude B: WV[rloc][t] = Wcg[orig][h*64..+64] . V[t][0..64) -> bf16;
  // t-loop staggered by c4 so the 4 concurrent rows hit distinct bank quads ----
  {
    #pragma unroll
    for (int s = 0; s < 3; ++s){
      const int rloc = rg*3 + s;                    // local row 0..383
      const int rpk  = half*384 + rloc;             // packed row 0..767
      const int orig = rpk + (rpk >= 256 ? 256 : 0);
      const u16* wp = Wcg + orig*512 + h*64;
      uint4 w0 = *(const uint4*)(wp),      w1 = *(const uint4*)(wp + 8);
      uint4 w2_ = *(const uint4*)(wp + 16), w3 = *(const uint4*)(wp + 24);
      uint4 w4 = *(const uint4*)(wp + 32), w5 = *(const uint4*)(wp + 40);
      uint4 w6 = *(const uint4*)(wp + 48), w7 = *(const uint4*)(wp + 56);
      for (int jj = 0; jj < 32; ++jj){
        const int t = c4*32 + ((jj + 2*c4) & 31);
        const float4* vv = (const float4*)(lK + t*68);
        float acc = dot8(w0, vv[0], vv[1])  + dot8(w1, vv[2], vv[3])
                  + dot8(w2_, vv[4], vv[5]) + dot8(w3, vv[6], vv[7])
                  + dot8(w4, vv[8], vv[9])  + dot8(w5, vv[10], vv[11])
                  + dot8(w6, vv[12], vv[13])+ dot8(w7, vv[14], vv[15]);
        lWV[rloc*136 + t] = f2bf(acc);
      }
    }
  }
  __syncthreads();
  // ---- prelude C: K -> lK (overwrites V temp) ----
  {
    const float* gK = kv + h*8192;
    for (int i = tid; i < 2048; i += 512){
      const int r = i >> 4, c = i & 15;
      *(float4*)(lK + r*68 + c*4) = *(const float4*)(gK + r*64 + c*4);
    }
  }

  // ---- persistent weights -> VGPRs (48/thread) ----
  float4 wq[8];   // Wqh row h*64+d, cols ko*32..+32
  {
    const float* p = Wqh + (h*64 + d)*256 + ko*32;
    #pragma unroll
    for (int j = 0; j < 8; ++j) wq[j] = *(const float4*)(p + 4*j);
  }
  uint4 w2[4];    // W2m packed row r2, cols c8*32..+32 (tid<384)
  {
    const int orig2 = r2 + (r2 >= 256 ? 256 : 0);
    const u16* p = W2m + (tid < 384 ? orig2*256 + c8*32 : 0);
    #pragma unroll
    for (int j = 0; j < 4; ++j) w2[j] = *(const uint4*)(p + 8*j);
  }
  // biases
  const float bq0 = bq[h*64 + d];
  const float bq1 = biasws[h*64 + d];
  const float bmd = bmel[h*64 + (tid >> 6)*8 + ((tid & 63) >> 3)];  // mel-gap mapping
  float bgi0=0, bgg0=0, bgo0=0, bgi1=0, bgg1=0, bgo1=0;
  if (tid < 256){
    bgi0 = biasws[ 512 + tid]; bgg0 = biasws[1024 + tid]; bgo0 = biasws[1280 + tid];
    bgi1 = biasws[1536 + tid]; bgg1 = biasws[2048 + tid]; bgo1 = biasws[2304 + tid];
  }
  float4 wst4 = {0.f,0.f,0.f,0.f};
  if (h == 0 && half == 0 && tid < 64) wst4 = *(const float4*)(Wstop + tid*4);
  const float bst = bstop[0];

  if (tid < 256) l_h[tid] = 0.f;
  if (tid < 288) l_hw[tid] = 0.f;
  float hreg = 0.f;
  __syncthreads();

  int rot = 0;
  for (int t = 0; t < 1000; ++t){
    float* buf = Gbuf + (rot*16 + b)*768;
    // ---- P1: q partials (all) + W2m partials -> direct aadd (tid<384) ----
    {
      const float4* hh = (const float4*)(l_h + ko*32);
      l_qt[ko][d] = dot8f(wq[0], wq[1], hh[0], hh[1]) + dot8f(wq[2], wq[3], hh[2], hh[3])
                  + dot8f(wq[4], wq[5], hh[4], hh[5]) + dot8f(wq[6], wq[7], hh[6], hh[7]);
    }
    if (tid < 384){
      const float4* hh = (const float4*)(l_hw + c8*36);
      float w2p = dot8(w2[0], hh[0], hh[1]) + dot8(w2[1], hh[2], hh[3])
                + dot8(w2[2], hh[4], hh[5]) + dot8(w2[3], hh[6], hh[7]);
      w2p += __shfl_xor(w2p, 1);
      w2p += __shfl_xor(w2p, 2);
      w2p += __shfl_xor(w2p, 4);               // combine 8 col-chunks
      if (c8 == 0) aadd(buf + r2, w2p);
    }
    __syncthreads();
    // ---- P2+P3: q assemble, QK^T, softmax — all in wave 0 ----
    if (tid < 64){
      float qq = (t == 0 ? bq0 : bq1);
      #pragma unroll
      for (int k = 0; k < 8; ++k) qq += l_qt[k][tid];
      l_q[tid] = qq;
      __asm__ __volatile__("s_waitcnt lgkmcnt(0)" ::: "memory");
      const float* kr0 = lK + tid*68;
      const float* kr1 = lK + (tid + 64)*68;
      float s0 = 0.f, s1 = 0.f;
      #pragma unroll
      for (int k = 0; k < 64; k += 8){
        float4 qa = *(const float4*)(l_q + k), qb = *(const float4*)(l_q + k + 4);
        s0 += dot8f(*(const float4*)(kr0 + k), *(const float4*)(kr0 + k + 4), qa, qb);
        s1 += dot8f(*(const float4*)(kr1 + k), *(const float4*)(kr1 + k + 4), qa, qb);
      }
      s0 *= 0.125f; s1 *= 0.125f;
      float m = fmaxf(s0, s1);
      #pragma unroll
      for (int off = 32; off; off >>= 1) m = fmaxf(m, __shfl_xor(m, off));
      float p0 = __expf(s0 - m), p1 = __expf(s1 - m);
      float ss = p0 + p1;
      #pragma unroll
      for (int off = 32; off; off >>= 1) ss += __shfl_xor(ss, off);
      l_p[tid] = p0; l_p[tid + 64] = p1;
      if (tid == 0){ l_r[0] = ss; l_r[1] = 1.f/ss; }
    }
    __syncthreads();
    // ---- P5: row-per-lane WV@p (conflict-free lK-pattern reads) ----
    if (tid < 384){
      const float invS = l_r[1];
      const u16* wr = lWV + tid*136;             // consecutive lanes, 272B stride
      const float4* pp = (const float4*)l_p;     // broadcast reads
      float acc = 0.f;
      #pragma unroll 4
      for (int k = 0; k < 16; ++k)
        acc += dot8(*(const uint4*)(wr + 8*k), pp[2*k], pp[2*k+1]);
      aadd(buf + half*384 + tid, acc*invS);
    }
    // reset buffer of step t-2 (== buffer for step t+1) on idle threads;
    // safe: all readers of it finished before flag(t), which we've passed.
    if (t >= 2 && tid >= 464){
      int rr = rot + 1; if (rr == 3) rr = 0;
      afstore(Gbuf + (rr*16 + b)*768 + sidx*48 + (tid - 464), 0.f);
    }
    bar_arrive(bflag, sidx, t+1);                // drains adds + reset, then flag
    // ---- gap (hidden under RT, SYNC-FREE): partner wait @t==1, mel/stop t-1 ----
    if (t == 1) bar_wait(bars + (b ^ 1)*512, 16, 1);  // partner preludes done
    if (half == 0 && t > 0){
      const int ln = tid & 63;
      const int dd = (tid >> 6)*8 + (ln >> 3), cc = ln & 7;
      const float* pm = Wmel + (h*64 + dd)*256 + cc*32;
      const float4* hh = (const float4*)(l_hw + cc*36);  // staggered, conflict-free
      float mp = dot8f(*(const float4*)(pm),      *(const float4*)(pm + 4),  hh[0], hh[1])
               + dot8f(*(const float4*)(pm + 8),  *(const float4*)(pm + 12), hh[2], hh[3])
               + dot8f(*(const float4*)(pm + 16), *(const float4*)(pm + 20), hh[4], hh[5])
               + dot8f(*(const float4*)(pm + 24), *(const float4*)(pm + 28), hh[6], hh[7]);
      mp += __shfl_xor(mp, 1); mp += __shfl_xor(mp, 2); mp += __shfl_xor(mp, 4);
      if (cc == 0) out_mel[((size_t)b*1000 + (t-1))*512 + h*64 + dd] = mp + bmd;
      if (h == 0 && tid < 64){
        const float4 h4v = *(const float4*)(l_h + tid*4);
        float sp = wst4.x*h4v.x + wst4.y*h4v.y + wst4.z*h4v.z + wst4.w*h4v.w;
        #pragma unroll
        for (int off = 32; off; off >>= 1) sp += __shfl_xor(sp, off);
        if (tid == 0) out_stop[b*1000 + (t-1)] = sp + bst;
      }
    }
    bar_wait(bflag, 16, t+1);                    // one RT per step
    // ---- P6: redundant h_t from summed gates (f-gates skipped) ----
    if (tid < 256){
      float gi = (t == 0 ? bgi0 : bgi1) + afload(buf + tid);
      float gg = (t == 0 ? bgg0 : bgg1) + afload(buf + 256 + tid);
      float go = (t == 0 ? bgo0 : bgo1) + afload(buf + 512 + tid);
      float c = sigm(gi) * tanhf(gg);            // decoder c_prev == 0 every step
      hreg = sigm(go) * tanhf(c);
      l_h[tid] = hreg;
      l_hw[(tid >> 5)*36 + (tid & 31)] = hreg;
    }
    __syncthreads();
    rot = (rot == 2) ? 0 : rot + 1;
  }

  // ---- epilogue: mel/stop for t=999; publish probs; head-avg attn ----
  if (half == 0){
    const int ln = tid & 63;
    const int dd = (tid >> 6)*8 + (ln >> 3), cc = ln & 7;
    const float* pm = Wmel + (h*64 + dd)*256 + cc*32;
    const float4* hh = (const float4*)(l_hw + cc*36);
    float mp = dot8f(*(const float4*)(pm),      *(const float4*)(pm + 4),  hh[0], hh[1])
             + dot8f(*(const float4*)(pm + 8),  *(const float4*)(pm + 12), hh[2], hh[3])
             + dot8f(*(const float4*)(pm + 16), *(const float4*)(pm + 20), hh[4], hh[5])
             + dot8f(*(const float4*)(pm + 24), *(const float4*)(pm + 28), hh[6], hh[7]);
    mp += __shfl_xor(mp, 1); mp += __shfl_xor(mp, 2); mp += __shfl_xor(mp, 4);
    if (cc == 0) out_mel[((size_t)b*1000 + 999)*512 + h*64 + dd] = mp + bmd;
    if (h == 0 && tid < 64){
      const float4 h4v = *(const float4*)(l_h + tid*4);
      float sp = wst4.x*h4v.x + wst4.y*h4v.y + wst4.z*h4v.z + wst4.w*h4v.w;
      #pragma unroll
      for (int off = 32; off; off >>= 1) sp += __shfl_xor(sp, off);
      if (tid == 0) out_stop[b*1000 + 999] = sp + bst;
    }
    if (tid < 128)   // l_p/l_r hold step-999 values; normalize here
      afstore(probs + (b*8 + h)*128 + tid, l_p[tid] / l_r[0]);
  }
  bar_arrive(bflag, sidx, 1001);                 // probs drained before flag
  if (h == 0 && half == 0){
    bar_wait(bflag, 16, 1001);
    if (tid < 128){
      float ssum = 0.f;
      #pragma unroll
      for (int hh = 0; hh < 8; ++hh) ssum += afload(probs + (b*8 + hh)*128 + tid);
      out_attn[b*128 + tid] = ssum * 0.125f;
    }
  }
}

extern "C" void kernel_launch(void* const* d_in, const int* in_sizes, int n_in,
                              void* d_out, int out_size, void* d_ws, size_t ws_size,
                              hipStream_t stream){
  const int*   tok = (const int*)d_in[0];
  const int*   spk = (const int*)d_in[1];
  const float* emb_text = (const float*)d_in[2];
  const float* emb_spk  = (const float*)d_in[3];
  const float* WihF = (const float*)d_in[4];
  const float* WhhF = (const float*)d_in[5];
  const float* bihF = (const float*)d_in[6];
  const float* bhhF = (const float*)d_in[7];
  const float* WihB = (const float*)d_in[8];
  const float* WhhB = (const float*)d_in[9];
  const float* bihB = (const float*)d_in[10];
  const float* bhhB = (const float*)d_in[11];
  const float* Wq = (const float*)d_in[12];
  const float* bq = (const float*)d_in[13];
  const float* Wk = (const float*)d_in[14];
  const float* bk = (const float*)d_in[15];
  const float* Wv = (const float*)d_in[16];
  const float* bv = (const float*)d_in[17];
  const float* Wo = (const float*)d_in[18];
  const float* bo = (const float*)d_in[19];
  const float* decW = (const float*)d_in[20];
  /* d_in[21] dec_Whh dead (state re-zeroed every step) */
  const float* bih = (const float*)d_in[22];
  const float* bhh = (const float*)d_in[23];
  const float* Wmel = (const float*)d_in[24];
  const float* bmel = (const float*)d_in[25];
  const float* Wstop = (const float*)d_in[26];
  const float* bstop = (const float*)d_in[27];

  char* ws = (char*)d_ws;
  int*   bars   = (int*)(ws + WS_BAR);
  float* Gbuf   = (float*)(ws + WS_GBUF);
  float* hbuf   = (float*)(ws + WS_HBUF);
  float* probs  = (float*)(ws + WS_PROBS);
  float* biasws = (float*)(ws + WS_BIAS);
  u16*   W2m    = (u16*)(ws + WS_W2M);
  float* Wqh    = (float*)(ws + WS_WQH);
  u16*   Wcg    = (u16*)(ws + WS_WCG);

  float* outf = (float*)d_out;
  float* encA = outf + OF_ENC_A;
  float* encB = outf + OF_ENC_B;
  float* xwf  = outf + OF_XWF;
  float* xwb  = outf + OF_XWB;

  k_init <<<32,   256, 0, stream>>>(bars, hbuf);
  k_xw   <<<2048, 256, 0, stream>>>(tok, spk, emb_text, emb_spk,
                                    WihF, bihF, bhhF, WihB, bihB, bhhB, xwf, xwb);
  k_enc  <<<256,  128, 0, stream>>>(xwf, xwb, WhhF, WhhB, encA, encB, bars);
  k_fuse <<<896,  256, 0, stream>>>(decW, Wo, Wmel, Wq, Wcg, W2m, Wqh);
  k_bias <<<6,    256, 0, stream>>>(Wq, bq, bmel, decW, bo, bih, bhh, biasws);
  k_proj <<<1024, 256, 0, stream>>>(encA, encB, Wk, bk, Wv, bv, outf);
  k_decode<<<256, 512, 0, stream>>>(Wqh, Wcg, W2m, Wmel, bmel, Wstop, bstop,
                                    bq, biasws, Gbuf, probs, bars, outf);
}

// Round 8
// 6618.027 us; speedup vs baseline: 1.0498x; 1.0498x over previous
//
#include <hip/hip_runtime.h>
#include <hip/hip_bf16.h>

// TTS: embed -> BiLSTM encoder -> K/V proj -> 1000-step autoregressive decode.
// v9 decode (hybrid: v6's cheap math + v8's cheap structure):
//  - Measured: time tracks critical-path VALU (v6 16.8%@5657 < v7 23.8%@5810
//    < v8 26.4%@5942); WV doubled gate MACs (128-dim vs 64-dim contraction).
//    Revert to PV+register-Wcg (24.5K bf16 MACs) and compute ctx INSIDE the
//    softmax wave: lane d does ctx[d]=sum_t p_t V[d][t]/S from lV row-per-lane
//    (2-way bank = free; l_p broadcast; intra-wave lgkmcnt, no barrier).
//    P4/P4b and their syncs vanish; lWV gone (LDS ~74KB, 128-reg regime).
//  - Bank model refined (v6/v8 counters): b128 LDS ops process in 16-lane
//    phases; 68/132/136-word strides give 2-way within a phase = free.
//  - Mel split across halves (32 dims each, balances barrier skew); stop on
//    (h0,half1); Gbuf rot-3 reset moved into P1 on idle lanes.
//  - 256 blocks = (b,h,half) x 512 thr; resident weights wq32+wcg24+w2m16=72
//    VGPR (v6-proven 124-reg fit). ONE RT/step: per-batch 768-float atomicAdd
//    accum, flag barrier (16 arrivals), redundant h_t everywhere. f-gates
//    skipped (c_prev==0). t==1 partner wait guards mel vs K/V-slot alias.
// Sync: fence-free flag barriers; agent-scope RELAXED atomics. fp32 except
// bf16 Wcg/W2m.

typedef unsigned short u16;
typedef unsigned int   u32;
#define DI __device__ __forceinline__

// ---- ws layout (bytes) ----
static constexpr size_t WS_BAR   = 0;              // int flag lines: [0,32KB) decode, 64KB+ enc
static constexpr size_t WS_GBUF  = 64*1024;        // fp32 [3][16][768] 144KB (zeroed by k_init)
static constexpr size_t WS_HBUF  = 192*1024;       // legacy zero region
static constexpr size_t WS_PROBS = 208*1024;       // fp32 [16][8][128] 64KB
static constexpr size_t WS_BIAS  = 272*1024;       // fp32 bqp[512]|bg0[1024]|bgp[1024]
static constexpr size_t WS_W2M   = 320*1024;       // bf16 [1024][256] 512KB
static constexpr size_t WS_WQH   = 832*1024;       // fp32 [512][256]  512KB
static constexpr size_t WS_WCG   = 1344*1024;      // bf16 [1024][512] 1MB -> 2368KB

// ---- d_out scratch (float indices; d_out = 8,210,048 floats) ----
static constexpr size_t OF_ENC_A = 262144;         // fp32 [8][128][512] b=0..7
static constexpr size_t OF_ENC_B = 1286144;        // fp32 [8][128][512] b=8..15
static constexpr size_t OF_XWF   = 4015744;        // fp32 [2048][1024]
static constexpr size_t OF_XWB   = 6112896;        // fp32 [2048][1024] -> 8210048
// K/V slot (batch pair p=b>>1, sub s=b&1): outf + p*1024000 + s*131072 (K then V^T)

DI float bf2f(u16 u){ union{u32 i; float f;} v; v.i = ((u32)u)<<16; return v.f; }
DI u16 f2bf(float f){ union{float f; u32 i;} v; v.f = f;
  u32 r = v.i + 0x7fffu + ((v.i>>16)&1u); return (u16)(r>>16); }
DI float2 bf2x(u32 u){ union{u32 i; float f;} a,b; a.i = u<<16; b.i = u & 0xffff0000u;
  float2 r; r.x = a.f; r.y = b.f; return r; }
DI float dot8(uint4 wv, float4 a, float4 b){   // bf16 weights x fp32 acts
  float2 w0 = bf2x(wv.x), w1 = bf2x(wv.y), w2 = bf2x(wv.z), w3 = bf2x(wv.w);
  return w0.x*a.x + w0.y*a.y + w1.x*a.z + w1.y*a.w
       + w2.x*b.x + w2.y*b.y + w3.x*b.z + w3.y*b.w;
}
DI float dot8f(float4 wa, float4 wb, float4 a, float4 b){
  return wa.x*a.x + wa.y*a.y + wa.z*a.z + wa.w*a.w
       + wb.x*b.x + wb.y*b.y + wb.z*b.z + wb.w*b.w;
}
DI float sigm(float x){ return 1.f/(1.f + __expf(-x)); }

// agent-scope relaxed atomics: coherence-point access, no fence needed.
DI float afload(const float* p){
  return __hip_atomic_load(p, __ATOMIC_RELAXED, __HIP_MEMORY_SCOPE_AGENT);
}
DI void afstore(float* p, float v){
  __hip_atomic_store(p, v, __ATOMIC_RELAXED, __HIP_MEMORY_SCOPE_AGENT);
}
DI void aadd(float* p, float v){
  __hip_atomic_fetch_add(p, v, __ATOMIC_RELAXED, __HIP_MEMORY_SCOPE_AGENT);
}

// ---- fence-free flag barrier ----
DI void bar_arrive(int* flags, int myidx, int t){
  __syncthreads();
  if (threadIdx.x == 0){
    __builtin_amdgcn_s_waitcnt(0);
    __hip_atomic_store(flags + myidx*32, t, __ATOMIC_RELAXED, __HIP_MEMORY_SCOPE_AGENT);
  }
}
DI void bar_wait(int* flags, int n, int t){
  if (threadIdx.x < 64){
    const int idx = threadIdx.x & (n-1);
    int v = __hip_atomic_load(flags + idx*32, __ATOMIC_RELAXED, __HIP_MEMORY_SCOPE_AGENT);
    while (__any(v < t)){
      __builtin_amdgcn_s_sleep(1);
      if (v < t)
        v = __hip_atomic_load(flags + idx*32, __ATOMIC_RELAXED, __HIP_MEMORY_SCOPE_AGENT);
    }
  }
  __asm__ __volatile__("" ::: "memory");
  __syncthreads();
}

__global__ __launch_bounds__(256) void k_init(int* bars, float* hbuf){
  const int i = blockIdx.x*256 + threadIdx.x;   // 32 blocks
  for (int k = i; k < 49152; k += 32*256) bars[k] = 0;
  if (i < 4096) hbuf[i] = 0.f;
}

// fused embed + x@Wih.T + biases -> xw fp32. 2048 blocks.
__global__ __launch_bounds__(256) void k_xw(
    const int* __restrict__ tok, const int* __restrict__ spk,
    const float* __restrict__ et, const float* __restrict__ es,
    const float* __restrict__ WihF, const float* __restrict__ bihF, const float* __restrict__ bhhF,
    const float* __restrict__ WihB, const float* __restrict__ bihB, const float* __restrict__ bhhB,
    float* __restrict__ xwf, float* __restrict__ xwb){
  const int tid = threadIdx.x, bi = blockIdx.x;
  const int dir = bi & 1, jc = (bi >> 1) & 3, btg = bi >> 3;
  const int j = jc*256 + tid;
  const float* W = (dir ? WihB : WihF) + j*256;
  const float bias = (dir ? bihB : bihF)[j] + (dir ? bhhB : bhhF)[j];
  float* xw = dir ? xwb : xwf;

  __shared__ __align__(16) float lx[8][256];
  #pragma unroll
  for (int r = 0; r < 8; ++r){
    const int bt = btg*8 + r;
    lx[r][tid] = et[tok[bt]*256 + tid] + es[spk[bt>>7]*256 + tid];
  }
  __syncthreads();

  float acc[8];
  #pragma unroll
  for (int k2 = 0; k2 < 8; ++k2) acc[k2] = bias;
  for (int h = 0; h < 256; h += 8){
    float4 w0 = *(const float4*)(W + h);
    float4 w1 = *(const float4*)(W + h + 4);
    #pragma unroll
    for (int k2 = 0; k2 < 8; ++k2)
      acc[k2] += dot8f(w0, w1, *(const float4*)(&lx[k2][h]), *(const float4*)(&lx[k2][h+4]));
  }
  #pragma unroll
  for (int k2 = 0; k2 < 8; ++k2) xw[(btg*8 + k2)*1024 + j] = acc[k2];
}

// Wcg = W1@Wo -> bf16 [1024,512]; W2m = W2@Wmel -> bf16 [1024,256];
// Wqh = Wq@Wmel -> fp32 [512,256]. 896 blocks.
__global__ __launch_bounds__(256) void k_fuse(
    const float* __restrict__ decW, const float* __restrict__ Wo,
    const float* __restrict__ Wmel, const float* __restrict__ Wq,
    u16* __restrict__ Wcg, u16* __restrict__ W2m, float* __restrict__ Wqh){
  const int tid = threadIdx.x, blk = blockIdx.x;
  float acc[4] = {0.f,0.f,0.f,0.f};
  if (blk < 512){
    const int g0 = (blk >> 1)*4, e = (blk & 1)*256 + tid;
    for (int jj = 0; jj < 512; ++jj){
      float wo = Wo[jj*512 + e];
      #pragma unroll
      for (int i2 = 0; i2 < 4; ++i2) acc[i2] += decW[(g0+i2)*1024 + jj] * wo;
    }
    #pragma unroll
    for (int i2 = 0; i2 < 4; ++i2) Wcg[(g0+i2)*512 + e] = f2bf(acc[i2]);
  } else if (blk < 768){
    const int g0 = (blk - 512)*4, h = tid;
    for (int m = 0; m < 512; ++m){
      float wm = Wmel[m*256 + h];
      #pragma unroll
      for (int i2 = 0; i2 < 4; ++i2) acc[i2] += decW[(g0+i2)*1024 + 512 + m] * wm;
    }
    #pragma unroll
    for (int i2 = 0; i2 < 4; ++i2) W2m[(g0+i2)*256 + h] = f2bf(acc[i2]);
  } else {
    const int j0 = (blk - 768)*4, h = tid;
    for (int e = 0; e < 512; ++e){
      float wm = Wmel[e*256 + h];
      #pragma unroll
      for (int i2 = 0; i2 < 4; ++i2) acc[i2] += Wq[(j0+i2)*512 + e] * wm;
    }
    #pragma unroll
    for (int i2 = 0; i2 < 4; ++i2) Wqh[(j0+i2)*256 + h] = acc[i2];
  }
}

__global__ __launch_bounds__(256) void k_bias(
    const float* __restrict__ Wq, const float* __restrict__ bq, const float* __restrict__ bmel,
    const float* __restrict__ decW, const float* __restrict__ bo,
    const float* __restrict__ bih, const float* __restrict__ bhh, float* __restrict__ biasws){
  const int o = blockIdx.x*256 + threadIdx.x;   // 6 blocks -> 1536
  if (o < 512){
    float s = bq[o];
    for (int e = 0; e < 512; ++e) s += Wq[o*512 + e] * bmel[e];
    biasws[o] = s;                               // bq' = Wq@bmel + bq
  } else {
    const int gr = o - 512;
    float s1 = bih[gr] + bhh[gr];
    for (int jj = 0; jj < 512; ++jj) s1 += decW[gr*1024 + jj] * bo[jj];
    biasws[512 + gr] = s1;                       // bg0 = W1@bo + bih + bhh
    float s2 = s1;
    for (int m = 0; m < 512; ++m) s2 += decW[gr*1024 + 512 + m] * bmel[m];
    biasws[1536 + gr] = s2;                      // bg' = bg0 + W2@bmel
  }
}

// persistent BiLSTM encoder: 32 groups (dir,b) x 8 WGs x 128 thr. fp32.
__global__ __launch_bounds__(128) void k_enc(
    const float* __restrict__ xwf, const float* __restrict__ xwb,
    const float* __restrict__ WhhF, const float* __restrict__ WhhB,
    float* encA, float* encB, int* bars){
  const int tid = threadIdx.x;
  const int xcd = blockIdx.x & 7, sl = blockIdx.x >> 3;
  const int grp = xcd*4 + (sl >> 3);
  const int w = sl & 7;
  const int dir = grp & 1, b = grp >> 1;
  int* bar = bars + (16 + grp)*1024;
  const float* Whh = dir ? WhhB : WhhF;
  const float* xw = dir ? xwb : xwf;
  float* encb = (b < 8 ? encA : encB) + (size_t)(b & 7)*65536;
  const int q = tid >> 5, ii = tid & 31;
  const int j = q*256 + w*32 + ii;
  const float* wr = Whh + j*256;

  __shared__ __align__(16) float l_h[256];
  __shared__ float l_g[4][32];
  __shared__ float l_c[32];
  if (tid < 32) l_c[tid] = 0.f;
  __syncthreads();

  for (int it = 0; it < 128; ++it){
    const int ts = dir ? (127 - it) : it;
    float acc = xw[(b*128 + ts)*1024 + j];
    if (it > 0){
      const int tp = dir ? (ts + 1) : (ts - 1);
      const float* hp = encb + tp*512 + dir*256;
      for (int i = tid; i < 256; i += 128) l_h[i] = afload(hp + i);
      __syncthreads();
      #pragma unroll 4
      for (int k = 0; k < 256; k += 8)
        acc += dot8f(*(const float4*)(wr + k), *(const float4*)(wr + k + 4),
                     *(const float4*)(&l_h[k]), *(const float4*)(&l_h[k + 4]));
    }
    l_g[q][ii] = acc;
    __syncthreads();
    if (tid < 32){
      float ig = l_g[0][tid], fg = l_g[1][tid], gg = l_g[2][tid], og = l_g[3][tid];
      float c = sigm(fg)*l_c[tid] + sigm(ig)*tanhf(gg);
      l_c[tid] = c;
      afstore(encb + ts*512 + dir*256 + w*32 + tid, sigm(og)*tanhf(c));
    }
    bar_arrive(bar, w, it+1);
    bar_wait(bar, 8, it+1);
  }
}

// K,V projections fp32 -> per-pair slot in d_out. 1024 blocks.
__global__ __launch_bounds__(256) void k_proj(
    const float* __restrict__ encA, const float* __restrict__ encB,
    const float* __restrict__ Wk, const float* __restrict__ bk,
    const float* __restrict__ Wv, const float* __restrict__ bv,
    float* outf){
  const int tid = threadIdx.x, x = blockIdx.x;
  const int role = x & 1, dc = (x >> 1) & 1, btg = x >> 2;
  const int row = dc*256 + tid;
  const float* W = (role ? Wv : Wk) + row*512;
  const float bias = (role ? bv : bk)[row];
  const int b = (btg*8) >> 7;
  const float* eb = (b < 8 ? encA : encB) + (size_t)(b & 7)*65536;
  float acc[8];
  #pragma unroll
  for (int k2 = 0; k2 < 8; ++k2) acc[k2] = bias;
  for (int e = 0; e < 512; e += 8){
    float4 wa = *(const float4*)(W + e);
    float4 wb = *(const float4*)(W + e + 4);
    #pragma unroll
    for (int k2 = 0; k2 < 8; ++k2){
      const float* ep = eb + ((btg*8 + k2) & 127)*512 + e;
      acc[k2] += dot8f(wa, wb, *(const float4*)(ep), *(const float4*)(ep + 4));
    }
  }
  const int head = row >> 6, dd = row & 63;
  float* kv = outf + (size_t)(b >> 1)*1024000 + (size_t)(b & 1)*131072;
  #pragma unroll
  for (int k2 = 0; k2 < 8; ++k2){
    const int ts = (btg*8 + k2) & 127;
    if (role == 0) kv[head*8192 + ts*64 + dd] = acc[k2];
    else           kv[65536 + head*8192 + dd*128 + ts] = acc[k2];
  }
}

// persistent decoder v9: 256 blocks = (b,h,half) x 512 thr. ctx computed in
// the softmax wave; Wcg in regs; one RT/step; sync-free balanced mel gap.
__global__ __launch_bounds__(512) void k_decode(
    const float* __restrict__ Wqh,   // [512][256] fp32
    const u16*   __restrict__ Wcg,   // [1024][512] bf16
    const u16*   __restrict__ W2m,   // [1024][256] bf16
    const float* __restrict__ Wmel,  // [512][256] fp32 (streamed per step)
    const float* __restrict__ bmel,
    const float* __restrict__ Wstop, const float* __restrict__ bstop,
    const float* __restrict__ bq,    // original bq [512]
    const float* __restrict__ biasws,// bqp[512] | bg0[1024] | bgp[1024]
    float* Gbuf,                     // [3][16][768] gate accumulators (zeroed)
    float* probs, int* bars,
    float* out){                     // K/V slots alias mel region (prelude-only reads)
  const int tid = threadIdx.x;
  const int b = blockIdx.x & 15, sidx = blockIdx.x >> 4;   // batch, slot
  const int h = sidx >> 1, half = sidx & 1;                // head, row-half
  const int d = tid & 63, ko = tid >> 6;                   // 64 dims x 8 k-chunks
  int* bflag = bars + b*512;
  float* out_mel  = out;
  float* out_stop = out + 8192000;
  float* out_attn = out + 8208000;

  // lK: fp32 [128][68]; lV: fp32 [64][132] — both strides 2-way/free for b128
  // (16-lane phase bank model, verified by v6/v8 counters).
  __shared__ __align__(16) float lK[128*68];
  __shared__ __align__(16) float lV[64*132];
  __shared__ __align__(16) float l_h[256];
  __shared__ __align__(16) float l_hw[8*36];    // staggered replica: chunk c at l_hw+c*36
  __shared__ __align__(16) float l_q[64];
  __shared__ __align__(16) float l_p[128];      // UNNORMALIZED exp(s-M)
  __shared__ __align__(16) float l_ct[64];      // normalized ctx
  __shared__ __align__(16) float l_qt[8][64];   // q partials
  __shared__ float l_r[2];                      // [0]=S (for epilogue probs)

  const float* kv = out + (size_t)(b >> 1)*1024000 + (size_t)(b & 1)*131072;
  const int rg = tid >> 2, c4 = tid & 3;        // Wcg roles: rows rg*3..+2, cols c4*16..+16
  const int rw = tid >> 3, c8 = tid & 7;        // w2m roles
  const int r2 = half*384 + h*48 + rw;          // w2m packed row

  // ---- prelude: K -> lK, V^T -> lV (direct f4 copies) ----
  {
    const float* gK = kv + h*8192;
    for (int i = tid; i < 2048; i += 512){
      const int r = i >> 4, c = i & 15;
      *(float4*)(lK + r*68 + c*4) = *(const float4*)(gK + r*64 + c*4);
    }
    const float* gV = kv + 65536 + h*8192;
    for (int i = tid; i < 2048; i += 512){
      const int r = i >> 5, c = i & 31;
      *(float4*)(lV + r*132 + c*4) = *(const float4*)(gV + r*128 + c*4);
    }
  }

  // ---- persistent weights -> VGPRs (72/thread; read once for 1000 steps) ----
  float4 wq[8];   // Wqh row h*64+d, cols ko*32..+32  (32 VGPR)
  {
    const float* p = Wqh + (h*64 + d)*256 + ko*32;
    #pragma unroll
    for (int j = 0; j < 8; ++j) wq[j] = *(const float4*)(p + 4*j);
  }
  // Wcg: this half's 384 packed rows {i,g,o}\f, head cols h*64..+64 (24 VGPR)
  uint4 wcg[3][2];
  #pragma unroll
  for (int s = 0; s < 3; ++s){
    const int r = half*384 + rg*3 + s;           // packed row 0..767
    const int orig = r + (r >= 256 ? 256 : 0);   // skip dead f-rows
    const u16* p = Wcg + orig*512 + h*64 + c4*16;
    wcg[s][0] = *(const uint4*)(p);
    wcg[s][1] = *(const uint4*)(p + 8);
  }
  uint4 w2[4];    // W2m packed row r2, cols c8*32..+32 (tid<384; 16 VGPR)
  {
    const int orig2 = r2 + (r2 >= 256 ? 256 : 0);
    const u16* p = W2m + (tid < 384 ? orig2*256 + c8*32 : 0);
    #pragma unroll
    for (int j = 0; j < 4; ++j) w2[j] = *(const uint4*)(p + 8*j);
  }
  // biases
  const float bq0 = bq[h*64 + d];
  const float bq1 = biasws[h*64 + d];
  const float bmd = bmel[h*64 + half*32 + ((tid & 255) >> 3)];   // gap mel bias
  float bgi0=0, bgg0=0, bgo0=0, bgi1=0, bgg1=0, bgo1=0;
  if (tid < 256){
    bgi0 = biasws[ 512 + tid]; bgg0 = biasws[1024 + tid]; bgo0 = biasws[1280 + tid];
    bgi1 = biasws[1536 + tid]; bgg1 = biasws[2048 + tid]; bgo1 = biasws[2304 + tid];
  }
  float4 wst4 = {0.f,0.f,0.f,0.f};
  if (h == 0 && half == 1 && tid < 64) wst4 = *(const float4*)(Wstop + tid*4);
  const float bst = bstop[0];

  if (tid < 256) l_h[tid] = 0.f;
  if (tid < 288) l_hw[tid] = 0.f;
  float hreg = 0.f;
  __syncthreads();

  int rot = 0;
  for (int t = 0; t < 1000; ++t){
    float* buf = Gbuf + (rot*16 + b)*768;
    // ---- P1: q partials (all) + W2m partials -> aadd (tid<384) + reset ----
    {
      const float4* hh = (const float4*)(l_h + ko*32);
      l_qt[ko][d] = dot8f(wq[0], wq[1], hh[0], hh[1]) + dot8f(wq[2], wq[3], hh[2], hh[3])
                  + dot8f(wq[4], wq[5], hh[4], hh[5]) + dot8f(wq[6], wq[7], hh[6], hh[7]);
    }
    if (tid < 384){
      const float4* hh = (const float4*)(l_hw + c8*36);
      float w2p = dot8(w2[0], hh[0], hh[1]) + dot8(w2[1], hh[2], hh[3])
                + dot8(w2[2], hh[4], hh[5]) + dot8(w2[3], hh[6], hh[7]);
      w2p += __shfl_xor(w2p, 1);
      w2p += __shfl_xor(w2p, 2);
      w2p += __shfl_xor(w2p, 4);               // combine 8 col-chunks
      if (c8 == 0) aadd(buf + r2, w2p);
    } else if (t >= 2 && tid >= 432 && tid < 480){
      // reset buffer of step t-2 (== buffer for t+1): all readers finished
      // before flag(t), which this block has passed (end of step t-1).
      int rr = rot + 1; if (rr == 3) rr = 0;
      afstore(Gbuf + (rr*16 + b)*768 + sidx*48 + (tid - 432), 0.f);
    }
    __syncthreads();
    // ---- wave0: q assemble, QK^T, softmax, ctx — no internal barriers ----
    if (tid < 64){
      float qq = (t == 0 ? bq0 : bq1);
      #pragma unroll
      for (int k = 0; k < 8; ++k) qq += l_qt[k][tid];
      l_q[tid] = qq;
      __asm__ __volatile__("s_waitcnt lgkmcnt(0)" ::: "memory");
      const float* kr0 = lK + tid*68;
      const float* kr1 = lK + (tid + 64)*68;
      float s0 = 0.f, s1 = 0.f;
      #pragma unroll
      for (int k = 0; k < 64; k += 8){
        float4 qa = *(const float4*)(l_q + k), qb = *(const float4*)(l_q + k + 4);
        s0 += dot8f(*(const float4*)(kr0 + k), *(const float4*)(kr0 + k + 4), qa, qb);
        s1 += dot8f(*(const float4*)(kr1 + k), *(const float4*)(kr1 + k + 4), qa, qb);
      }
      s0 *= 0.125f; s1 *= 0.125f;
      float m = fmaxf(s0, s1);
      #pragma unroll
      for (int off = 32; off; off >>= 1) m = fmaxf(m, __shfl_xor(m, off));
      float p0 = __expf(s0 - m), p1 = __expf(s1 - m);
      float ss = p0 + p1;
      #pragma unroll
      for (int off = 32; off; off >>= 1) ss += __shfl_xor(ss, off);
      l_p[tid] = p0; l_p[tid + 64] = p1;
      __asm__ __volatile__("s_waitcnt lgkmcnt(0)" ::: "memory");
      // ctx[d]: row-per-lane over lV (2-way free), l_p broadcast
      const float* vr = lV + tid*132;
      float cs = 0.f;
      #pragma unroll
      for (int k = 0; k < 128; k += 8)
        cs += dot8f(*(const float4*)(vr + k), *(const float4*)(vr + k + 4),
                    *(const float4*)(l_p + k), *(const float4*)(l_p + k + 4));
      l_ct[tid] = cs / ss;
      if (tid == 0) l_r[0] = ss;
    }
    __syncthreads();
    // ---- P5: Wcg gate partials (registers) -> per-batch aadd ----
    {
      const float4* ct = (const float4*)(l_ct + c4*16);
      float4 c0 = ct[0], c1 = ct[1], c2 = ct[2], c3 = ct[3];
      float pr0 = dot8(wcg[0][0], c0, c1) + dot8(wcg[0][1], c2, c3);
      float pr1 = dot8(wcg[1][0], c0, c1) + dot8(wcg[1][1], c2, c3);
      float pr2 = dot8(wcg[2][0], c0, c1) + dot8(wcg[2][1], c2, c3);
      pr0 += __shfl_xor(pr0, 1); pr0 += __shfl_xor(pr0, 2);
      pr1 += __shfl_xor(pr1, 1); pr1 += __shfl_xor(pr1, 2);
      pr2 += __shfl_xor(pr2, 1); pr2 += __shfl_xor(pr2, 2);
      if (c4 == 0){
        const int rb = half*384 + rg*3;
        aadd(buf + rb,     pr0);
        aadd(buf + rb + 1, pr1);
        aadd(buf + rb + 2, pr2);
      }
    }
    bar_arrive(bflag, sidx, t+1);                // drains adds, then flag
    // ---- gap (hidden under RT, sync-free): partner wait @t==1, mel/stop ----
    if (t == 1) bar_wait(bars + (b ^ 1)*512, 16, 1);  // partner preludes done
    if (t > 0){
      if (tid < 256){
        const int dd = half*32 + (tid >> 3), cc = tid & 7;
        const float* pm = Wmel + (h*64 + dd)*256 + cc*32;
        const float4* hh = (const float4*)(l_hw + cc*36);  // staggered, free
        float mp = dot8f(*(const float4*)(pm),      *(const float4*)(pm + 4),  hh[0], hh[1])
                 + dot8f(*(const float4*)(pm + 8),  *(const float4*)(pm + 12), hh[2], hh[3])
                 + dot8f(*(const float4*)(pm + 16), *(const float4*)(pm + 20), hh[4], hh[5])
                 + dot8f(*(const float4*)(pm + 24), *(const float4*)(pm + 28), hh[6], hh[7]);
        mp += __shfl_xor(mp, 1); mp += __shfl_xor(mp, 2); mp += __shfl_xor(mp, 4);
        if (cc == 0) out_mel[((size_t)b*1000 + (t-1))*512 + h*64 + dd] = mp + bmd;
      }
      if (h == 0 && half == 1 && tid < 64){
        const float4 h4v = *(const float4*)(l_h + tid*4);
        float sp = wst4.x*h4v.x + wst4.y*h4v.y + wst4.z*h4v.z + wst4.w*h4v.w;
        #pragma unroll
        for (int off = 32; off; off >>= 1) sp += __shfl_xor(sp, off);
        if (tid == 0) out_stop[b*1000 + (t-1)] = sp + bst;
      }
    }
    bar_wait(bflag, 16, t+1);                    // one RT per step
    // ---- P6: redundant h_t from summed gates (f-gates skipped) ----
    if (tid < 256){
      float gi = (t == 0 ? bgi0 : bgi1) + afload(buf + tid);
      float gg = (t == 0 ? bgg0 : bgg1) + afload(buf + 256 + tid);
      float go = (t == 0 ? bgo0 : bgo1) + afload(buf + 512 + tid);
      float c = sigm(gi) * tanhf(gg);            // decoder c_prev == 0 every step
      hreg = sigm(go) * tanhf(c);
      l_h[tid] = hreg;
      l_hw[(tid >> 5)*36 + (tid & 31)] = hreg;
    }
    __syncthreads();
    rot = (rot == 2) ? 0 : rot + 1;
  }

  // ---- epilogue: mel/stop for t=999; publish probs; head-avg attn ----
  if (tid < 256){
    const int dd = half*32 + (tid >> 3), cc = tid & 7;
    const float* pm = Wmel + (h*64 + dd)*256 + cc*32;
    const float4* hh = (const float4*)(l_hw + cc*36);
    float mp = dot8f(*(const float4*)(pm),      *(const float4*)(pm + 4),  hh[0], hh[1])
             + dot8f(*(const float4*)(pm + 8),  *(const float4*)(pm + 12), hh[2], hh[3])
             + dot8f(*(const float4*)(pm + 16), *(const float4*)(pm + 20), hh[4], hh[5])
             + dot8f(*(const float4*)(pm + 24), *(const float4*)(pm + 28), hh[6], hh[7]);
    mp += __shfl_xor(mp, 1); mp += __shfl_xor(mp, 2); mp += __shfl_xor(mp, 4);
    if (cc == 0) out_mel[((size_t)b*1000 + 999)*512 + h*64 + dd] = mp + bmd;
  }
  if (h == 0 && half == 1 && tid < 64){
    const float4 h4v = *(const float4*)(l_h + tid*4);
    float sp = wst4.x*h4v.x + wst4.y*h4v.y + wst4.z*h4v.z + wst4.w*h4v.w;
    #pragma unroll
    for (int off = 32; off; off >>= 1) sp += __shfl_xor(sp, off);
    if (tid == 0) out_stop[b*1000 + 999] = sp + bst;
  }
  if (half == 0 && tid < 128)   // l_p/l_r hold step-999 values; normalize here
    afstore(probs + (b*8 + h)*128 + tid, l_p[tid] / l_r[0]);
  bar_arrive(bflag, sidx, 1001);                 // probs drained before flag
  if (h == 0 && half == 0){
    bar_wait(bflag, 16, 1001);
    if (tid < 128){
      float ssum = 0.f;
      #pragma unroll
      for (int hh = 0; hh < 8; ++hh) ssum += afload(probs + (b*8 + hh)*128 + tid);
      out_attn[b*128 + tid] = ssum * 0.125f;
    }
  }
}

extern "C" void kernel_launch(void* const* d_in, const int* in_sizes, int n_in,
                              void* d_out, int out_size, void* d_ws, size_t ws_size,
                              hipStream_t stream){
  const int*   tok = (const int*)d_in[0];
  const int*   spk = (const int*)d_in[1];
  const float* emb_text = (const float*)d_in[2];
  const float* emb_spk  = (const float*)d_in[3];
  const float* WihF = (const float*)d_in[4];
  const float* WhhF = (const float*)d_in[5];
  const float* bihF = (const float*)d_in[6];
  const float* bhhF = (const float*)d_in[7];
  const float* WihB = (const float*)d_in[8];
  const float* WhhB = (const float*)d_in[9];
  const float* bihB = (const float*)d_in[10];
  const float* bhhB = (const float*)d_in[11];
  const float* Wq = (const float*)d_in[12];
  const float* bq = (const float*)d_in[13];
  const float* Wk = (const float*)d_in[14];
  const float* bk = (const float*)d_in[15];
  const float* Wv = (const float*)d_in[16];
  const float* bv = (const float*)d_in[17];
  const float* Wo = (const float*)d_in[18];
  const float* bo = (const float*)d_in[19];
  const float* decW = (const float*)d_in[20];
  /* d_in[21] dec_Whh dead (state re-zeroed every step) */
  const float* bih = (const float*)d_in[22];
  const float* bhh = (const float*)d_in[23];
  const float* Wmel = (const float*)d_in[24];
  const float* bmel = (const float*)d_in[25];
  const float* Wstop = (const float*)d_in[26];
  const float* bstop = (const float*)d_in[27];

  char* ws = (char*)d_ws;
  int*   bars   = (int*)(ws + WS_BAR);
  float* Gbuf   = (float*)(ws + WS_GBUF);
  float* hbuf   = (float*)(ws + WS_HBUF);
  float* probs  = (float*)(ws + WS_PROBS);
  float* biasws = (float*)(ws + WS_BIAS);
  u16*   W2m    = (u16*)(ws + WS_W2M);
  float* Wqh    = (float*)(ws + WS_WQH);
  u16*   Wcg    = (u16*)(ws + WS_WCG);

  float* outf = (float*)d_out;
  float* encA = outf + OF_ENC_A;
  float* encB = outf + OF_ENC_B;
  float* xwf  = outf + OF_XWF;
  float* xwb  = outf + OF_XWB;

  k_init <<<32,   256, 0, stream>>>(bars, hbuf);
  k_xw   <<<2048, 256, 0, stream>>>(tok, spk, emb_text, emb_spk,
                                    WihF, bihF, bhhF, WihB, bihB, bhhB, xwf, xwb);
  k_enc  <<<256,  128, 0, stream>>>(xwf, xwb, WhhF, WhhB, encA, encB, bars);
  k_fuse <<<896,  256, 0, stream>>>(decW, Wo, Wmel, Wq, Wcg, W2m, Wqh);
  k_bias <<<6,    256, 0, stream>>>(Wq, bq, bmel, decW, bo, bih, bhh, biasws);
  k_proj <<<1024, 256, 0, stream>>>(encA, encB, Wk, bk, Wv, bv, outf);
  k_decode<<<256, 512, 0, stream>>>(Wqh, Wcg, W2m, Wmel, bmel, Wstop, bstop,
                                    bq, biasws, Gbuf, probs, bars, outf);
}